// Round 3
// baseline (965.925 us; speedup 1.0000x reference)
//
#include <hip/hip_runtime.h>
#include <math.h>

#define NLAYER 3
#define LREADx 512
#define NSEQx  96

__device__ __forceinline__ float fsigmoid(float v){ return 1.f/(1.f+__expf(-v)); }
__device__ __forceinline__ float fsoftplus(float v){ return fmaxf(v,0.f) + __logf(1.f + __expf(-fabsf(v))); }

template<int CTRL>
__device__ __forceinline__ float dpp_add(float v){
  int x = __builtin_amdgcn_update_dpp(0, __float_as_int(v), CTRL, 0xF, 0xF, true);
  return v + __int_as_float(x);
}

// ---------------- expander: h = reads @ ew.T + eb ----------------
__global__ __launch_bounds__(256) void k_exp(const float* __restrict__ reads,
    const float* __restrict__ ew, const float* __restrict__ eb, float* __restrict__ h){
  int idx = blockIdx.x*256 + threadIdx.x;     // NROWS*64
  int d = idx & 63;
  int row = idx >> 6;
  float4 r4 = *(const float4*)(reads + (size_t)row*4);
  float4 w4 = *(const float4*)(ew + d*4);
  h[idx] = fmaf(r4.x,w4.x, fmaf(r4.y,w4.y, fmaf(r4.z,w4.z, fmaf(r4.w,w4.w, eb[d]))));
}

// ---------------- fused in_proj + causal conv(k=4) + silu + z-gate precompute ----------------
__global__ __launch_bounds__(256) void k_xzc(const float* __restrict__ h,
    const float* __restrict__ w, const float* __restrict__ cw, const float* __restrict__ cb,
    float* __restrict__ x, float* __restrict__ zsil){
  __shared__ float xp[35][128];
  int j = threadIdx.x;
  int row0 = blockIdx.x*32;
  int l0 = row0 & 511;
  bool isx = j < 128;
  float4 wr[16];
  #pragma unroll
  for (int k=0;k<16;k++) wr[k] = *(const float4*)(w + j*64 + k*4);
  if (isx){
    #pragma unroll
    for (int r=0;r<3;r++){
      float a = 0.f;
      if (l0 != 0){
        const float4* hr = (const float4*)(h + (size_t)(row0-3+r)*64);
        #pragma unroll
        for (int k=0;k<16;k++){
          float4 hv = hr[k];
          a = fmaf(hv.x,wr[k].x, fmaf(hv.y,wr[k].y, fmaf(hv.z,wr[k].z, fmaf(hv.w,wr[k].w, a))));
        }
      }
      xp[r][j] = a;
    }
  }
  for (int r=0;r<32;r++){
    const float4* hr = (const float4*)(h + (size_t)(row0+r)*64);
    float a = 0.f;
    #pragma unroll
    for (int k=0;k<16;k++){
      float4 hv = hr[k];
      a = fmaf(hv.x,wr[k].x, fmaf(hv.y,wr[k].y, fmaf(hv.z,wr[k].z, fmaf(hv.w,wr[k].w, a))));
    }
    if (isx) xp[3+r][j] = a;
    else     zsil[(size_t)(row0+r)*128 + (j-128)] = a * fsigmoid(a);
  }
  __syncthreads();
  int c = j & 127, half = j >> 7;
  float4 w4 = *(const float4*)(cw + c*4);
  float bv = cb[c];
  #pragma unroll
  for (int r=half*16; r<half*16+16; r++){
    float a = fmaf(xp[r][c],w4.x, fmaf(xp[r+1][c],w4.y, fmaf(xp[r+2][c],w4.z,
              fmaf(xp[r+3][c],w4.w, bv))));
    x[(size_t)(row0+r)*128 + c] = a * fsigmoid(a);
  }
}

// ---------------- x_proj (K=128,N=36) + dt=softplus(..) + B/C interleave ----------------
__global__ __launch_bounds__(256) void k_xd(const float* __restrict__ x,
    const float* __restrict__ xwT, const float* __restrict__ dtw,
    const float* __restrict__ dtb, float* __restrict__ dt, float* __restrict__ bc){
  __shared__ float4 xd03[256];
  __shared__ float  bcs[256][33];
  int t = threadIdx.x;
  int row = blockIdx.x*256 + t;
  float acc[36];
  #pragma unroll
  for (int c=0;c<36;c++) acc[c]=0.f;
  const float4* xr = (const float4*)(x + (size_t)row*128);
  for (int k4=0;k4<32;k4++){
    float4 xv = xr[k4];
    float xa[4] = {xv.x, xv.y, xv.z, xv.w};
    #pragma unroll
    for (int kk=0;kk<4;kk++){
      const float* wk = xwT + (k4*4+kk)*36;   // uniform -> SMEM
      #pragma unroll
      for (int c=0;c<36;c++) acc[c] = fmaf(xa[kk], wk[c], acc[c]);
    }
  }
  xd03[t] = make_float4(acc[0],acc[1],acc[2],acc[3]);
  #pragma unroll
  for (int nn=0;nn<16;nn++){ bcs[t][2*nn] = acc[4+nn]; bcs[t][2*nn+1] = acc[20+nn]; }
  __syncthreads();
  int d = t & 127, half = t >> 7;
  float4 w4 = *(const float4*)(dtw + d*4);
  float bv = dtb[d];
  size_t row0 = (size_t)blockIdx.x*256;
  for (int rr=half; rr<256; rr+=2){
    float4 s4 = xd03[rr];
    float v = fmaf(s4.x,w4.x, fmaf(s4.y,w4.y, fmaf(s4.z,w4.z, fmaf(s4.w,w4.w, bv))));
    dt[(row0+rr)*128 + d] = fsoftplus(v);
  }
  for (int i=t; i<256*32; i+=256){
    int r = i >> 5, cc = i & 31;
    bc[(row0+r)*32 + cc] = bcs[r][cc];
  }
}

// ---------------- selective scan ----------------
__global__ __launch_bounds__(256) void k_scan(const float* __restrict__ dt,
    const float* __restrict__ x, const float* __restrict__ zsil,
    const float* __restrict__ bc, const float* __restrict__ alog,
    const float* __restrict__ Dp, float* __restrict__ y){
  __shared__ float2 dd[64*16];
  __shared__ float2 bcs[64*16];
  __shared__ float  xs[64*16];
  __shared__ float  zss[64*16];
  __shared__ float  ys[64*16];
  int t = threadIdx.x;
  int b  = blockIdx.x >> 3;
  int dg = blockIdx.x & 7;
  int dl = t >> 4, n = t & 15;
  float aL = -__expf(alog[(dg*16+dl)*16 + n]) * 1.44269504f;   // A * log2(e)
  float Dv = Dp[dg*16 + (t & 15)];
  float hs = 0.f;
  int lt = t >> 2, q = t & 3;
  size_t rowbase = ((size_t)b*LREADx)*128 + dg*16;
  size_t bcbase  = ((size_t)b*LREADx)*32;
  for (int c=0;c<8;c++){
    int l0 = c*64;
    { // stage 64 timesteps
      size_t g = rowbase + (size_t)(l0+lt)*128 + q*4;
      float4 d4 = *(const float4*)(dt + g);
      float4 x4 = *(const float4*)(x + g);
      float4 z4 = *(const float4*)(zsil + g);
      int e = lt*16 + q*4;
      dd[e+0] = make_float2(d4.x, d4.x*x4.x);
      dd[e+1] = make_float2(d4.y, d4.y*x4.y);
      dd[e+2] = make_float2(d4.z, d4.z*x4.z);
      dd[e+3] = make_float2(d4.w, d4.w*x4.w);
      *(float4*)(xs+e)  = x4;
      *(float4*)(zss+e) = z4;
      size_t gb = bcbase + (size_t)(l0+lt)*32 + q*4;
      float4 b0 = *(const float4*)(bc + gb);
      float4 b1 = *(const float4*)(bc + gb + 16);
      *(float4*)((float*)bcs + lt*32 + q*4)      = b0;
      *(float4*)((float*)bcs + lt*32 + 16 + q*4) = b1;
    }
    __syncthreads();
    #pragma unroll 16
    for (int l=0;l<64;l++){
      float2 dv = dd[l*16 + dl];
      float2 bv = bcs[l*16 + n];
      float e = __builtin_amdgcn_exp2f(dv.x * aL);
      hs = fmaf(e, hs, dv.y * bv.x);
      float p = hs * bv.y;
      p = dpp_add<0x121>(p);   // row_ror:1
      p = dpp_add<0x122>(p);   // row_ror:2
      p = dpp_add<0x124>(p);   // row_ror:4
      p = dpp_add<0x128>(p);   // row_ror:8
      if (n == 0) ys[l*16 + dl] = p;
    }
    __syncthreads();
    #pragma unroll
    for (int i=0;i<4;i++){
      int idx = t + i*256;
      float v = (ys[idx] + xs[idx]*Dv) * zss[idx];
      int le = idx >> 4, de = idx & 15;
      y[rowbase + (size_t)(l0+le)*128 + de] = v;
    }
    __syncthreads();
  }
}

// ---------------- out proj + LayerNorm + ReLU ----------------
// lane = row. y tile staged in LDS (XOR-swizzled float4 -> conflict-free b128);
// weights via wave-uniform index (readfirstlane) -> s_load path. j-split x2 per row;
// exact two-pass LN with LDS partial exchange.
__global__ __launch_bounds__(256) void k_out(const float* __restrict__ y,
    const float* __restrict__ ow, const float* __restrict__ lnw,
    const float* __restrict__ lnb, float* __restrict__ h){
  __shared__ float4 yt[2048];       // 128 rows x 16 float4 (one k-half), swizzled
  __shared__ float  psA[128][2];
  __shared__ float  psB[128][2];
  int t = threadIdx.x;
  int w = t >> 6;
  int jh = __builtin_amdgcn_readfirstlane(w >> 1);   // 0/1: which 32-col half
  int rl = (t & 63) + ((w & 1) << 6);                // 0..127: local row
  int row0 = blockIdx.x*128;
  float acc[32];
  #pragma unroll
  for (int j=0;j<32;j++) acc[j] = 0.f;
  const float4* yg = (const float4*)y;
  for (int kc=0;kc<2;kc++){
    #pragma unroll
    for (int i=0;i<8;i++){
      int f = i*256 + t;
      int r = f >> 4, q = f & 15;
      yt[r*16 + (q ^ (r & 7))] = yg[(size_t)(row0+r)*32 + kc*16 + q];
    }
    __syncthreads();
    float4 yv[16];
    #pragma unroll
    for (int q=0;q<16;q++) yv[q] = yt[rl*16 + (q ^ (rl & 7))];
    #pragma unroll
    for (int j=0;j<32;j++){
      const float4* wj = (const float4*)(ow + (size_t)(jh*32+j)*128 + kc*64);  // uniform -> s_load
      float a = acc[j];
      #pragma unroll
      for (int q=0;q<16;q++){
        float4 w4 = wj[q];
        float4 yq = yv[q];
        a = fmaf(yq.x,w4.x, fmaf(yq.y,w4.y, fmaf(yq.z,w4.z, fmaf(yq.w,w4.w, a))));
      }
      acc[j] = a;
    }
    __syncthreads();
  }
  // two-pass LN across the two column halves
  float s1 = 0.f;
  #pragma unroll
  for (int j=0;j<32;j++) s1 += acc[j];
  psA[rl][jh] = s1;
  __syncthreads();
  float m = (psA[rl][0] + psA[rl][1]) * (1.f/64.f);
  float s2 = 0.f;
  #pragma unroll
  for (int j=0;j<32;j++){ float d = acc[j]-m; s2 += d*d; }
  psB[rl][jh] = s2;
  __syncthreads();
  float inv = rsqrtf((psB[rl][0] + psB[rl][1])*(1.f/64.f) + 1e-5f);
  float* hr = h + (size_t)(row0+rl)*64 + jh*32;
  #pragma unroll
  for (int j4=0;j4<8;j4++){
    float4 o;
    float* op = (float*)&o;
    #pragma unroll
    for (int e=0;e<4;e++){
      int j = j4*4+e;
      float v = (acc[j]-m)*inv*lnw[jh*32+j] + lnb[jh*32+j];
      op[e] = fmaxf(v, 0.f);
    }
    *(float4*)(hr + j4*4) = o;
  }
}

// ---------------- mean + last pooling -> enc ----------------
__global__ __launch_bounds__(512) void k_pool(const float* __restrict__ h, float* __restrict__ enc){
  __shared__ float ps[8][64];
  int t = threadIdx.x;
  int w = t >> 6, d = t & 63;
  int b = blockIdx.x;
  const float* hb = h + (size_t)b*LREADx*64;
  float s = 0.f;
  #pragma unroll 8
  for (int i=0;i<64;i++) s += hb[(size_t)(w*64+i)*64 + d];
  ps[w][d] = s;
  __syncthreads();
  if (w == 0){
    float acc = 0.f;
    #pragma unroll
    for (int i=0;i<8;i++) acc += ps[i][d];
    enc[b*128 + d]      = acc * (1.f/512.f);
    enc[b*128 + 64 + d] = hb[(size_t)511*64 + d];
  }
}

// ---------------- q,k projections ----------------
__global__ __launch_bounds__(256) void k_qk(const float* __restrict__ enc,
    const int* __restrict__ sidx, const float* __restrict__ qw, const float* __restrict__ qb,
    const float* __restrict__ kw, const float* __restrict__ kb,
    float* __restrict__ qbuf, float* __restrict__ kbuf){
  int idx = blockIdx.x*256 + threadIdx.x;
  if (idx < NSEQx*64){
    int qi = idx >> 6, j = idx & 63;
    const float* er = enc + (size_t)sidx[qi]*128;
    const float* wr = qw + j*128;
    float a = qb[j];
    for (int k=0;k<32;k++){
      float4 e4 = *(const float4*)(er + k*4);
      float4 w4 = *(const float4*)(wr + k*4);
      a = fmaf(e4.x,w4.x, fmaf(e4.y,w4.y, fmaf(e4.z,w4.z, fmaf(e4.w,w4.w, a))));
    }
    qbuf[idx] = a;
  } else {
    int i2 = idx - NSEQx*64;
    int ki = i2 >> 6, j = i2 & 63;
    const float* er = enc + (size_t)ki*128;
    const float* wr = kw + j*128;
    float a = kb[j];
    for (int k=0;k<32;k++){
      float4 e4 = *(const float4*)(er + k*4);
      float4 w4 = *(const float4*)(wr + k*4);
      a = fmaf(e4.x,w4.x, fmaf(e4.y,w4.y, fmaf(e4.z,w4.z, fmaf(e4.w,w4.w, a))));
    }
    kbuf[i2] = a;
  }
}

// ---------------- scores ----------------
__global__ __launch_bounds__(256) void k_score(const float* __restrict__ qbuf,
    const float* __restrict__ kbuf, const float* __restrict__ mixw,
    const float* __restrict__ mixb, float* __restrict__ out){
  int idx = blockIdx.x*256 + threadIdx.x;
  int ki = idx & 127, qi = idx >> 7;
  const float* qr = qbuf + qi*64;
  const float* kr = kbuf + ki*64;
  float s[4];
  #pragma unroll
  for (int hh=0;hh<4;hh++){
    float a = 0.f;
    #pragma unroll
    for (int k=0;k<4;k++){
      float4 q4 = *(const float4*)(qr + hh*16 + k*4);
      float4 k4 = *(const float4*)(kr + hh*16 + k*4);
      a = fmaf(q4.x,k4.x, fmaf(q4.y,k4.y, fmaf(q4.z,k4.z, fmaf(q4.w,k4.w, a))));
    }
    s[hh] = fmaxf(a, 0.f);
  }
  float best = -1e30f;
  #pragma unroll
  for (int hh=0;hh<4;hh++){
    float v = mixb[hh];
    #pragma unroll
    for (int h2=0;h2<4;h2++) v = fmaf(s[h2], mixw[hh*4+h2], v);
    best = fmaxf(best, v);
  }
  out[idx] = best;
}

// ---------------- transpose x_proj_w once ----------------
__global__ __launch_bounds__(256) void k_trans(const float* __restrict__ xw, float* __restrict__ xwT){
  int i = threadIdx.x + blockIdx.x*256;
  if (i < NLAYER*36*128){
    int l = i / 4608, rem = i % 4608;
    int c = rem >> 7, k = rem & 127;
    xwT[l*4608 + k*36 + c] = xw[i];
  }
}

extern "C" void kernel_launch(void* const* d_in, const int* in_sizes, int n_in,
                              void* d_out, int out_size, void* d_ws, size_t ws_size,
                              hipStream_t stream) {
  (void)in_sizes; (void)n_in; (void)out_size; (void)ws_size;
  const float* reads = (const float*)d_in[0];
  const int*   sidx  = (const int*)d_in[1];
  const float* ew    = (const float*)d_in[2];
  const float* eb    = (const float*)d_in[3];
  const float* inw   = (const float*)d_in[4];
  const float* cw    = (const float*)d_in[5];
  const float* cb    = (const float*)d_in[6];
  const float* xw    = (const float*)d_in[7];
  const float* dtw   = (const float*)d_in[8];
  const float* dtb   = (const float*)d_in[9];
  const float* alog  = (const float*)d_in[10];
  const float* Dp    = (const float*)d_in[11];
  const float* ow    = (const float*)d_in[12];
  const float* lnw   = (const float*)d_in[13];
  const float* lnb   = (const float*)d_in[14];
  const float* qw    = (const float*)d_in[15];
  const float* qb    = (const float*)d_in[16];
  const float* kw    = (const float*)d_in[17];
  const float* kb    = (const float*)d_in[18];
  const float* mixw  = (const float*)d_in[19];
  const float* mixb  = (const float*)d_in[20];

  float* ws  = (float*)d_ws;
  float* h   = ws;                 // 4,194,304
  float* yx  = ws + 4194304;       // 8,388,608 (y)
  float* zs  = ws + 12582912;      // 8,388,608
  float* x   = ws + 20971520;      // 8,388,608
  float* dt  = ws + 29360128;      // 8,388,608
  float* bc  = ws + 37748736;      // 2,097,152
  float* enc = ws + 39845888;      // 16,384
  float* qk  = ws + 39862272;      // 6144 + 8192
  float* xwT = ws + 39876608;      // 13,824

  k_trans<<<54, 256, 0, stream>>>(xw, xwT);
  k_exp<<<16384, 256, 0, stream>>>(reads, ew, eb, h);
  for (int l = 0; l < NLAYER; l++){
    k_xzc <<<2048, 256, 0, stream>>>(h, inw + l*16384, cw + l*512, cb + l*128, x, zs);
    k_xd  <<<256, 256, 0, stream>>>(x, xwT + l*4608, dtw + l*512, dtb + l*128, dt, bc);
    k_scan<<<1024, 256, 0, stream>>>(dt, x, zs, bc, alog + l*2048, Dp + l*128, yx);
    k_out <<<512, 256, 0, stream>>>(yx, ow + l*8192, lnw + l*64, lnb + l*64, h);
  }
  k_pool <<<128, 512, 0, stream>>>(h, enc);
  k_qk   <<<56, 256, 0, stream>>>(enc, sidx, qw, qb, kw, kb, qk, qk + 6144);
  k_score<<<48, 256, 0, stream>>>(qk, qk + 6144, mixw, mixb, (float*)d_out);
}

// Round 5
// 822.296 us; speedup vs baseline: 1.1747x; 1.1747x over previous
//
#include <hip/hip_runtime.h>
#include <math.h>

#define NLAYER 3
#define LREADx 512
#define NSEQx  96

__device__ __forceinline__ float fsigmoid(float v){ return 1.f/(1.f+__expf(-v)); }
__device__ __forceinline__ float fsoftplus(float v){ return fmaxf(v,0.f) + __logf(1.f + __expf(-fabsf(v))); }

template<int CTRL>
__device__ __forceinline__ float dpp_add(float v){
  int x = __builtin_amdgcn_update_dpp(0, __float_as_int(v), CTRL, 0xF, 0xF, true);
  return v + __int_as_float(x);
}

// ---------------- expander: h = reads @ ew.T + eb ----------------
__global__ __launch_bounds__(256) void k_exp(const float* __restrict__ reads,
    const float* __restrict__ ew, const float* __restrict__ eb, float* __restrict__ h){
  int idx = blockIdx.x*256 + threadIdx.x;     // NROWS*64
  int d = idx & 63;
  int row = idx >> 6;
  float4 r4 = *(const float4*)(reads + (size_t)row*4);
  float4 w4 = *(const float4*)(ew + d*4);
  h[idx] = fmaf(r4.x,w4.x, fmaf(r4.y,w4.y, fmaf(r4.z,w4.z, fmaf(r4.w,w4.w, eb[d]))));
}

// ---------------- fused in_proj + causal conv(k=4) + silu + z-gate precompute ----------------
__global__ __launch_bounds__(256) void k_xzc(const float* __restrict__ h,
    const float* __restrict__ w, const float* __restrict__ cw, const float* __restrict__ cb,
    float* __restrict__ x, float* __restrict__ zsil){
  __shared__ float xp[35][128];
  int j = threadIdx.x;
  int row0 = blockIdx.x*32;
  int l0 = row0 & 511;
  bool isx = j < 128;
  float4 wr[16];
  #pragma unroll
  for (int k=0;k<16;k++) wr[k] = *(const float4*)(w + j*64 + k*4);
  if (isx){
    #pragma unroll
    for (int r=0;r<3;r++){
      float a = 0.f;
      if (l0 != 0){
        const float4* hr = (const float4*)(h + (size_t)(row0-3+r)*64);
        #pragma unroll
        for (int k=0;k<16;k++){
          float4 hv = hr[k];
          a = fmaf(hv.x,wr[k].x, fmaf(hv.y,wr[k].y, fmaf(hv.z,wr[k].z, fmaf(hv.w,wr[k].w, a))));
        }
      }
      xp[r][j] = a;
    }
  }
  for (int r=0;r<32;r++){
    const float4* hr = (const float4*)(h + (size_t)(row0+r)*64);
    float a = 0.f;
    #pragma unroll
    for (int k=0;k<16;k++){
      float4 hv = hr[k];
      a = fmaf(hv.x,wr[k].x, fmaf(hv.y,wr[k].y, fmaf(hv.z,wr[k].z, fmaf(hv.w,wr[k].w, a))));
    }
    if (isx) xp[3+r][j] = a;
    else     zsil[(size_t)(row0+r)*128 + (j-128)] = a * fsigmoid(a);
  }
  __syncthreads();
  int c = j & 127, half = j >> 7;
  float4 w4 = *(const float4*)(cw + c*4);
  float bv = cb[c];
  #pragma unroll
  for (int r=half*16; r<half*16+16; r++){
    float a = fmaf(xp[r][c],w4.x, fmaf(xp[r+1][c],w4.y, fmaf(xp[r+2][c],w4.z,
              fmaf(xp[r+3][c],w4.w, bv))));
    x[(size_t)(row0+r)*128 + c] = a * fsigmoid(a);
  }
}

// ---------------- x_proj (K=128,N=36) + dt=softplus(..) + B/C interleave ----------------
__global__ __launch_bounds__(256) void k_xd(const float* __restrict__ x,
    const float* __restrict__ xwT, const float* __restrict__ dtw,
    const float* __restrict__ dtb, float* __restrict__ dt, float* __restrict__ bc){
  __shared__ float4 xd03[256];
  __shared__ float  bcs[256][33];
  int t = threadIdx.x;
  int row = blockIdx.x*256 + t;
  float acc[36];
  #pragma unroll
  for (int c=0;c<36;c++) acc[c]=0.f;
  const float4* xr = (const float4*)(x + (size_t)row*128);
  for (int k4=0;k4<32;k4++){
    float4 xv = xr[k4];
    float xa[4] = {xv.x, xv.y, xv.z, xv.w};
    #pragma unroll
    for (int kk=0;kk<4;kk++){
      const float* wk = xwT + (k4*4+kk)*36;   // uniform -> SMEM
      #pragma unroll
      for (int c=0;c<36;c++) acc[c] = fmaf(xa[kk], wk[c], acc[c]);
    }
  }
  xd03[t] = make_float4(acc[0],acc[1],acc[2],acc[3]);
  #pragma unroll
  for (int nn=0;nn<16;nn++){ bcs[t][2*nn] = acc[4+nn]; bcs[t][2*nn+1] = acc[20+nn]; }
  __syncthreads();
  int d = t & 127, half = t >> 7;
  float4 w4 = *(const float4*)(dtw + d*4);
  float bv = dtb[d];
  size_t row0 = (size_t)blockIdx.x*256;
  for (int rr=half; rr<256; rr+=2){
    float4 s4 = xd03[rr];
    float v = fmaf(s4.x,w4.x, fmaf(s4.y,w4.y, fmaf(s4.z,w4.z, fmaf(s4.w,w4.w, bv))));
    dt[(row0+rr)*128 + d] = fsoftplus(v);
  }
  for (int i=t; i<256*32; i+=256){
    int r = i >> 5, cc = i & 31;
    bc[(row0+r)*32 + cc] = bcs[r][cc];
  }
}

// ---------------- selective scan ----------------
__global__ __launch_bounds__(256) void k_scan(const float* __restrict__ dt,
    const float* __restrict__ x, const float* __restrict__ zsil,
    const float* __restrict__ bc, const float* __restrict__ alog,
    const float* __restrict__ Dp, float* __restrict__ y){
  __shared__ float2 dd[64*16];
  __shared__ float2 bcs[64*16];
  __shared__ float  xs[64*16];
  __shared__ float  zss[64*16];
  __shared__ float  ys[64*16];
  int t = threadIdx.x;
  int b  = blockIdx.x >> 3;
  int dg = blockIdx.x & 7;
  int dl = t >> 4, n = t & 15;
  float aL = -__expf(alog[(dg*16+dl)*16 + n]) * 1.44269504f;   // A * log2(e)
  float Dv = Dp[dg*16 + (t & 15)];
  float hs = 0.f;
  int lt = t >> 2, q = t & 3;
  size_t rowbase = ((size_t)b*LREADx)*128 + dg*16;
  size_t bcbase  = ((size_t)b*LREADx)*32;
  for (int c=0;c<8;c++){
    int l0 = c*64;
    { // stage 64 timesteps
      size_t g = rowbase + (size_t)(l0+lt)*128 + q*4;
      float4 d4 = *(const float4*)(dt + g);
      float4 x4 = *(const float4*)(x + g);
      float4 z4 = *(const float4*)(zsil + g);
      int e = lt*16 + q*4;
      dd[e+0] = make_float2(d4.x, d4.x*x4.x);
      dd[e+1] = make_float2(d4.y, d4.y*x4.y);
      dd[e+2] = make_float2(d4.z, d4.z*x4.z);
      dd[e+3] = make_float2(d4.w, d4.w*x4.w);
      *(float4*)(xs+e)  = x4;
      *(float4*)(zss+e) = z4;
      size_t gb = bcbase + (size_t)(l0+lt)*32 + q*4;
      float4 b0 = *(const float4*)(bc + gb);
      float4 b1 = *(const float4*)(bc + gb + 16);
      *(float4*)((float*)bcs + lt*32 + q*4)      = b0;
      *(float4*)((float*)bcs + lt*32 + 16 + q*4) = b1;
    }
    __syncthreads();
    #pragma unroll 16
    for (int l=0;l<64;l++){
      float2 dv = dd[l*16 + dl];
      float2 bv = bcs[l*16 + n];
      float e = __builtin_amdgcn_exp2f(dv.x * aL);
      hs = fmaf(e, hs, dv.y * bv.x);
      float p = hs * bv.y;
      p = dpp_add<0x121>(p);   // row_ror:1
      p = dpp_add<0x122>(p);   // row_ror:2
      p = dpp_add<0x124>(p);   // row_ror:4
      p = dpp_add<0x128>(p);   // row_ror:8
      if (n == 0) ys[l*16 + dl] = p;
    }
    __syncthreads();
    #pragma unroll
    for (int i=0;i<4;i++){
      int idx = t + i*256;
      float v = (ys[idx] + xs[idx]*Dv) * zss[idx];
      int le = idx >> 4, de = idx & 15;
      y[rowbase + (size_t)(l0+le)*128 + de] = v;
    }
    __syncthreads();
  }
}

// ---------------- out proj + LayerNorm + ReLU ----------------
// k_xzc-style: lane = output col (64), weights hoisted to VGPR once per block,
// y rows via wave-uniform s_load, one row at a time (all-scalar state),
// LN fused per row via 64-lane shuffle reduce. 4 waves x 8 rows = 32 rows/block.
__global__ __launch_bounds__(256) void k_out(const float* __restrict__ y,
    const float* __restrict__ ow, const float* __restrict__ lnw,
    const float* __restrict__ lnb, float* __restrict__ h){
  int t = threadIdx.x;
  int j = t & 63;
  int rg = __builtin_amdgcn_readfirstlane(t >> 6);
  int row0 = blockIdx.x*32 + rg*8;
  float4 wr[32];
  #pragma unroll
  for (int k=0;k<32;k++) wr[k] = *(const float4*)(ow + j*128 + k*4);
  float lw = lnw[j], lb = lnb[j];
  for (int r=0;r<8;r++){
    const float4* yr = (const float4*)(y + (size_t)(row0+r)*128);  // uniform -> s_load
    float a = 0.f;
    #pragma unroll
    for (int k=0;k<32;k++){
      float4 yv = yr[k];
      a = fmaf(yv.x,wr[k].x, fmaf(yv.y,wr[k].y, fmaf(yv.z,wr[k].z, fmaf(yv.w,wr[k].w, a))));
    }
    float s = a;
    #pragma unroll
    for (int off=1;off<64;off<<=1) s += __shfl_xor(s, off, 64);
    float m = s * (1.f/64.f);
    float dv = a - m;
    float s2 = dv*dv;
    #pragma unroll
    for (int off=1;off<64;off<<=1) s2 += __shfl_xor(s2, off, 64);
    float o = dv * rsqrtf(s2*(1.f/64.f) + 1e-5f) * lw + lb;
    h[(size_t)(row0+r)*64 + j] = fmaxf(o, 0.f);
  }
}

// ---------------- mean + last pooling -> enc ----------------
__global__ __launch_bounds__(512) void k_pool(const float* __restrict__ h, float* __restrict__ enc){
  __shared__ float ps[8][64];
  int t = threadIdx.x;
  int w = t >> 6, d = t & 63;
  int b = blockIdx.x;
  const float* hb = h + (size_t)b*LREADx*64;
  float s = 0.f;
  #pragma unroll 8
  for (int i=0;i<64;i++) s += hb[(size_t)(w*64+i)*64 + d];
  ps[w][d] = s;
  __syncthreads();
  if (w == 0){
    float acc = 0.f;
    #pragma unroll
    for (int i=0;i<8;i++) acc += ps[i][d];
    enc[b*128 + d]      = acc * (1.f/512.f);
    enc[b*128 + 64 + d] = hb[(size_t)511*64 + d];
  }
}

// ---------------- q,k projections ----------------
__global__ __launch_bounds__(256) void k_qk(const float* __restrict__ enc,
    const int* __restrict__ sidx, const float* __restrict__ qw, const float* __restrict__ qb,
    const float* __restrict__ kw, const float* __restrict__ kb,
    float* __restrict__ qbuf, float* __restrict__ kbuf){
  int idx = blockIdx.x*256 + threadIdx.x;
  if (idx < NSEQx*64){
    int qi = idx >> 6, j = idx & 63;
    const float* er = enc + (size_t)sidx[qi]*128;
    const float* wr = qw + j*128;
    float a = qb[j];
    for (int k=0;k<32;k++){
      float4 e4 = *(const float4*)(er + k*4);
      float4 w4 = *(const float4*)(wr + k*4);
      a = fmaf(e4.x,w4.x, fmaf(e4.y,w4.y, fmaf(e4.z,w4.z, fmaf(e4.w,w4.w, a))));
    }
    qbuf[idx] = a;
  } else {
    int i2 = idx - NSEQx*64;
    int ki = i2 >> 6, j = i2 & 63;
    const float* er = enc + (size_t)ki*128;
    const float* wr = kw + j*128;
    float a = kb[j];
    for (int k=0;k<32;k++){
      float4 e4 = *(const float4*)(er + k*4);
      float4 w4 = *(const float4*)(wr + k*4);
      a = fmaf(e4.x,w4.x, fmaf(e4.y,w4.y, fmaf(e4.z,w4.z, fmaf(e4.w,w4.w, a))));
    }
    kbuf[i2] = a;
  }
}

// ---------------- scores ----------------
__global__ __launch_bounds__(256) void k_score(const float* __restrict__ qbuf,
    const float* __restrict__ kbuf, const float* __restrict__ mixw,
    const float* __restrict__ mixb, float* __restrict__ out){
  int idx = blockIdx.x*256 + threadIdx.x;
  int ki = idx & 127, qi = idx >> 7;
  const float* qr = qbuf + qi*64;
  const float* kr = kbuf + ki*64;
  float s[4];
  #pragma unroll
  for (int hh=0;hh<4;hh++){
    float a = 0.f;
    #pragma unroll
    for (int k=0;k<4;k++){
      float4 q4 = *(const float4*)(qr + hh*16 + k*4);
      float4 k4 = *(const float4*)(kr + hh*16 + k*4);
      a = fmaf(q4.x,k4.x, fmaf(q4.y,k4.y, fmaf(q4.z,k4.z, fmaf(q4.w,k4.w, a))));
    }
    s[hh] = fmaxf(a, 0.f);
  }
  float best = -1e30f;
  #pragma unroll
  for (int hh=0;hh<4;hh++){
    float v = mixb[hh];
    #pragma unroll
    for (int h2=0;h2<4;h2++) v = fmaf(s[h2], mixw[hh*4+h2], v);
    best = fmaxf(best, v);
  }
  out[idx] = best;
}

// ---------------- transpose x_proj_w once ----------------
__global__ __launch_bounds__(256) void k_trans(const float* __restrict__ xw, float* __restrict__ xwT){
  int i = threadIdx.x + blockIdx.x*256;
  if (i < NLAYER*36*128){
    int l = i / 4608, rem = i % 4608;
    int c = rem >> 7, k = rem & 127;
    xwT[l*4608 + k*36 + c] = xw[i];
  }
}

extern "C" void kernel_launch(void* const* d_in, const int* in_sizes, int n_in,
                              void* d_out, int out_size, void* d_ws, size_t ws_size,
                              hipStream_t stream) {
  (void)in_sizes; (void)n_in; (void)out_size; (void)ws_size;
  const float* reads = (const float*)d_in[0];
  const int*   sidx  = (const int*)d_in[1];
  const float* ew    = (const float*)d_in[2];
  const float* eb    = (const float*)d_in[3];
  const float* inw   = (const float*)d_in[4];
  const float* cw    = (const float*)d_in[5];
  const float* cb    = (const float*)d_in[6];
  const float* xw    = (const float*)d_in[7];
  const float* dtw   = (const float*)d_in[8];
  const float* dtb   = (const float*)d_in[9];
  const float* alog  = (const float*)d_in[10];
  const float* Dp    = (const float*)d_in[11];
  const float* ow    = (const float*)d_in[12];
  const float* lnw   = (const float*)d_in[13];
  const float* lnb   = (const float*)d_in[14];
  const float* qw    = (const float*)d_in[15];
  const float* qb    = (const float*)d_in[16];
  const float* kw    = (const float*)d_in[17];
  const float* kb    = (const float*)d_in[18];
  const float* mixw  = (const float*)d_in[19];
  const float* mixb  = (const float*)d_in[20];

  float* ws  = (float*)d_ws;
  float* h   = ws;                 // 4,194,304
  float* yx  = ws + 4194304;       // 8,388,608 (y)
  float* zs  = ws + 12582912;      // 8,388,608
  float* x   = ws + 20971520;      // 8,388,608
  float* dt  = ws + 29360128;      // 8,388,608
  float* bc  = ws + 37748736;      // 2,097,152
  float* enc = ws + 39845888;      // 16,384
  float* qk  = ws + 39862272;      // 6144 + 8192
  float* xwT = ws + 39876608;      // 13,824

  k_trans<<<54, 256, 0, stream>>>(xw, xwT);
  k_exp<<<16384, 256, 0, stream>>>(reads, ew, eb, h);
  for (int l = 0; l < NLAYER; l++){
    k_xzc <<<2048, 256, 0, stream>>>(h, inw + l*16384, cw + l*512, cb + l*128, x, zs);
    k_xd  <<<256, 256, 0, stream>>>(x, xwT + l*4608, dtw + l*512, dtb + l*128, dt, bc);
    k_scan<<<1024, 256, 0, stream>>>(dt, x, zs, bc, alog + l*2048, Dp + l*128, yx);
    k_out <<<2048, 256, 0, stream>>>(yx, ow + l*8192, lnw + l*64, lnb + l*64, h);
  }
  k_pool <<<128, 512, 0, stream>>>(h, enc);
  k_qk   <<<56, 256, 0, stream>>>(enc, sidx, qw, qb, kw, kb, qk, qk + 6144);
  k_score<<<48, 256, 0, stream>>>(qk, qk + 6144, mixw, mixb, (float*)d_out);
}

// Round 6
// 777.088 us; speedup vs baseline: 1.2430x; 1.0582x over previous
//
#include <hip/hip_runtime.h>
#include <math.h>

#define NLAYER 3
#define LREADx 512
#define NSEQx  96

__device__ __forceinline__ float fsigmoid(float v){ return 1.f/(1.f+__expf(-v)); }
__device__ __forceinline__ float fsoftplus(float v){ return fmaxf(v,0.f) + __logf(1.f + __expf(-fabsf(v))); }

template<int CTRL>
__device__ __forceinline__ float dpp_add(float v){
  int x = __builtin_amdgcn_update_dpp(0, __float_as_int(v), CTRL, 0xF, 0xF, true);
  return v + __int_as_float(x);
}

__device__ __forceinline__ void gload16(const float* g, float* l){
  __builtin_amdgcn_global_load_lds(
      (const __attribute__((address_space(1))) void*)g,
      (__attribute__((address_space(3))) void*)l, 16, 0, 0);
}

// ---------------- expander: h = reads @ ew.T + eb ----------------
__global__ __launch_bounds__(256) void k_exp(const float* __restrict__ reads,
    const float* __restrict__ ew, const float* __restrict__ eb, float* __restrict__ h){
  int idx = blockIdx.x*256 + threadIdx.x;     // NROWS*64
  int d = idx & 63;
  int row = idx >> 6;
  float4 r4 = *(const float4*)(reads + (size_t)row*4);
  float4 w4 = *(const float4*)(ew + d*4);
  h[idx] = fmaf(r4.x,w4.x, fmaf(r4.y,w4.y, fmaf(r4.z,w4.z, fmaf(r4.w,w4.w, eb[d]))));
}

// ---------------- fused in_proj + causal conv(k=4) + silu + z-gate precompute ----------------
__global__ __launch_bounds__(256) void k_xzc(const float* __restrict__ h,
    const float* __restrict__ w, const float* __restrict__ cw, const float* __restrict__ cb,
    float* __restrict__ x, float* __restrict__ zsil){
  __shared__ float xp[35][128];
  int j = threadIdx.x;
  int row0 = blockIdx.x*32;
  int l0 = row0 & 511;
  bool isx = j < 128;
  float4 wr[16];
  #pragma unroll
  for (int k=0;k<16;k++) wr[k] = *(const float4*)(w + j*64 + k*4);
  if (isx){
    #pragma unroll
    for (int r=0;r<3;r++){
      float a = 0.f;
      if (l0 != 0){
        const float4* hr = (const float4*)(h + (size_t)(row0-3+r)*64);
        float a0=0.f, a1=0.f;
        #pragma unroll
        for (int k=0;k<16;k+=2){
          float4 h0 = hr[k], h1 = hr[k+1];
          a0 = fmaf(h0.x,wr[k].x, fmaf(h0.y,wr[k].y, fmaf(h0.z,wr[k].z, fmaf(h0.w,wr[k].w, a0))));
          a1 = fmaf(h1.x,wr[k+1].x, fmaf(h1.y,wr[k+1].y, fmaf(h1.z,wr[k+1].z, fmaf(h1.w,wr[k+1].w, a1))));
        }
        a = a0 + a1;
      }
      xp[r][j] = a;
    }
  }
  for (int r=0;r<32;r++){
    const float4* hr = (const float4*)(h + (size_t)(row0+r)*64);
    float a0=0.f, a1=0.f;
    #pragma unroll
    for (int k=0;k<16;k+=2){
      float4 h0 = hr[k], h1 = hr[k+1];
      a0 = fmaf(h0.x,wr[k].x, fmaf(h0.y,wr[k].y, fmaf(h0.z,wr[k].z, fmaf(h0.w,wr[k].w, a0))));
      a1 = fmaf(h1.x,wr[k+1].x, fmaf(h1.y,wr[k+1].y, fmaf(h1.z,wr[k+1].z, fmaf(h1.w,wr[k+1].w, a1))));
    }
    float a = a0 + a1;
    if (isx) xp[3+r][j] = a;
    else     zsil[(size_t)(row0+r)*128 + (j-128)] = a * fsigmoid(a);
  }
  __syncthreads();
  int c = j & 127, half = j >> 7;
  float4 w4 = *(const float4*)(cw + c*4);
  float bv = cb[c];
  #pragma unroll
  for (int r=half*16; r<half*16+16; r++){
    float a = fmaf(xp[r][c],w4.x, fmaf(xp[r+1][c],w4.y, fmaf(xp[r+2][c],w4.z,
              fmaf(xp[r+3][c],w4.w, bv))));
    x[(size_t)(row0+r)*128 + c] = a * fsigmoid(a);
  }
}

// ---------------- x_proj (K=128 split 2x64, N=36) + dt softplus + B/C interleave ----------------
// 512 blocks x 128 rows; thread t: row = t&127, k-half = t>>7 (wave-uniform).
__global__ __launch_bounds__(256) void k_xd(const float* __restrict__ x,
    const float* __restrict__ xwT, const float* __restrict__ dtw,
    const float* __restrict__ dtb, float* __restrict__ dt, float* __restrict__ bc){
  __shared__ float  accs[128][37];
  __shared__ float4 xd03[128];
  __shared__ float  bcs[128][33];
  int t = threadIdx.x;
  int r = t & 127, kh = t >> 7;
  int row = blockIdx.x*128 + r;
  float acc[36];
  #pragma unroll
  for (int c=0;c<36;c++) acc[c]=0.f;
  const float4* xr = (const float4*)(x + (size_t)row*128 + kh*64);
  for (int k4=0;k4<16;k4++){
    float4 xv = xr[k4];
    float xa[4] = {xv.x, xv.y, xv.z, xv.w};
    #pragma unroll
    for (int kk=0;kk<4;kk++){
      const float* wk = xwT + (kh*64 + k4*4+kk)*36;   // uniform per wave -> SMEM
      #pragma unroll
      for (int c=0;c<36;c++) acc[c] = fmaf(xa[kk], wk[c], acc[c]);
    }
  }
  if (kh == 1){
    #pragma unroll
    for (int c=0;c<36;c++) accs[r][c] = acc[c];
  }
  __syncthreads();
  if (kh == 0){
    #pragma unroll
    for (int c=0;c<36;c++) acc[c] += accs[r][c];
    xd03[r] = make_float4(acc[0],acc[1],acc[2],acc[3]);
    #pragma unroll
    for (int nn=0;nn<16;nn++){ bcs[r][2*nn] = acc[4+nn]; bcs[r][2*nn+1] = acc[20+nn]; }
  }
  __syncthreads();
  int d = t & 127, half = t >> 7;
  float4 w4 = *(const float4*)(dtw + d*4);
  float bv = dtb[d];
  size_t row0 = (size_t)blockIdx.x*128;
  for (int rr=half; rr<128; rr+=2){
    float4 s4 = xd03[rr];
    float v = fmaf(s4.x,w4.x, fmaf(s4.y,w4.y, fmaf(s4.z,w4.z, fmaf(s4.w,w4.w, bv))));
    dt[(row0+rr)*128 + d] = fsoftplus(v);
  }
  for (int i=t; i<128*32; i+=256){
    int rr = i >> 5, cc = i & 31;
    bc[(row0+rr)*32 + cc] = bcs[rr][cc];
  }
}

// ---------------- selective scan: async double-buffered staging ----------------
// block = (b, d-group of 16), grid b-major for XCD L2 reuse. thread = (dl, n).
// dt/x/bc double-buffered via global_load_lds prefetch; z single-buffered (same-iter use).
// counted vmcnt (never full drain mid-loop) + raw s_barrier.
__global__ __launch_bounds__(256) void k_scan(const float* __restrict__ dt,
    const float* __restrict__ x, const float* __restrict__ zsil,
    const float* __restrict__ bc, const float* __restrict__ alog,
    const float* __restrict__ Dp, float* __restrict__ y){
  __shared__ float dtb_[2][1024];
  __shared__ float xb [2][1024];
  __shared__ float bcb[2][2048];
  __shared__ float zb [1024];
  __shared__ float ys [1024];
  int t = threadIdx.x;
  int b  = blockIdx.x & 127;
  int dg = blockIdx.x >> 7;
  int w  = __builtin_amdgcn_readfirstlane(t >> 6);
  int ln = t & 63;
  int dl = t >> 4, n = t & 15;
  float aL = -__expf(alog[(dg*16+dl)*16 + n]) * 1.44269504f;   // A * log2(e)
  float Dv = Dp[dg*16 + n];
  float hs = 0.f;
  size_t rowbase = ((size_t)b*LREADx)*128 + dg*16;
  size_t bcbase  = ((size_t)b*LREADx)*32;
  // per-lane DMA source bases (chunk 0)
  const float* dtp = dt   + rowbase + (size_t)(w*16 + (ln>>2))*128 + (ln&3)*4;
  const float* xp_ = x    + rowbase + (size_t)(w*16 + (ln>>2))*128 + (ln&3)*4;
  const float* zp_ = zsil + rowbase + (size_t)(w*16 + (ln>>2))*128 + (ln&3)*4;
  const float* bp0 = bc + bcbase + (size_t)(w*16     + (ln>>3))*32 + (ln&7)*4;
  const float* bp1 = bc + bcbase + (size_t)(w*16 + 8 + (ln>>3))*32 + (ln&7)*4;

  // prologue: dt/x/bc for chunk 0
  {
    gload16(dtp, &dtb_[0][w*256]);
    gload16(xp_, &xb [0][w*256]);
    gload16(bp0, &bcb[0][w*512]);
    gload16(bp1, &bcb[0][w*512+256]);
  }
  for (int c=0;c<8;c++){
    int buf = c & 1;
    size_t off  = (size_t)c*64*128;
    size_t offb = (size_t)c*64*32;
    gload16(zp_ + off, &zb[w*256]);                    // z for THIS chunk
    if (c < 7){                                        // prefetch next chunk
      size_t o2  = off  + 64*128;
      size_t o2b = offb + 64*32;
      gload16(dtp + o2, &dtb_[buf^1][w*256]);
      gload16(xp_ + o2, &xb [buf^1][w*256]);
      gload16(bp0 + o2b, &bcb[buf^1][w*512]);
      gload16(bp1 + o2b, &bcb[buf^1][w*512+256]);
    }
    if (c < 7) asm volatile("s_waitcnt vmcnt(5)" ::: "memory");
    else       asm volatile("s_waitcnt vmcnt(1)" ::: "memory");
    __builtin_amdgcn_s_barrier();
    // ---- compute 64 steps from buf ----
    #pragma unroll 16
    for (int l=0;l<64;l++){
      float dtv = dtb_[buf][l*16 + dl];
      float xv  = xb [buf][l*16 + dl];
      float2 bv = *(const float2*)&bcb[buf][l*32 + 2*n];
      float e = __builtin_amdgcn_exp2f(dtv * aL);
      hs = fmaf(e, hs, dtv*xv*bv.x);
      float p = hs * bv.y;
      p = dpp_add<0x121>(p);   // row_ror:1
      p = dpp_add<0x122>(p);   // row_ror:2
      p = dpp_add<0x124>(p);   // row_ror:4
      p = dpp_add<0x128>(p);   // row_ror:8
      if (n == 0) ys[l*16 + dl] = p;
    }
    if (c < 7) asm volatile("s_waitcnt lgkmcnt(0) vmcnt(4)" ::: "memory");
    else       asm volatile("s_waitcnt lgkmcnt(0) vmcnt(0)" ::: "memory");
    __builtin_amdgcn_s_barrier();
    // ---- epilogue: y = (ys + x*D) * silu(z) ----
    #pragma unroll
    for (int i=0;i<4;i++){
      int idx = t + i*256;
      float v = (ys[idx] + xb[buf][idx]*Dv) * zb[idx];
      int le = idx >> 4, de = idx & 15;
      y[rowbase + (size_t)(c*64+le)*128 + de] = v;
    }
    asm volatile("s_waitcnt lgkmcnt(0)" ::: "memory");
    __builtin_amdgcn_s_barrier();
  }
}

// ---------------- out proj + LayerNorm + ReLU ----------------
__global__ __launch_bounds__(256) void k_out(const float* __restrict__ y,
    const float* __restrict__ ow, const float* __restrict__ lnw,
    const float* __restrict__ lnb, float* __restrict__ h){
  int t = threadIdx.x;
  int j = t & 63;
  int rg = __builtin_amdgcn_readfirstlane(t >> 6);
  int row0 = blockIdx.x*32 + rg*8;
  float4 wr[32];
  #pragma unroll
  for (int k=0;k<32;k++) wr[k] = *(const float4*)(ow + j*128 + k*4);
  float lw = lnw[j], lb = lnb[j];
  for (int r=0;r<8;r++){
    const float4* yr = (const float4*)(y + (size_t)(row0+r)*128);  // uniform -> s_load
    float a0=0.f, a1=0.f;
    #pragma unroll
    for (int k=0;k<32;k+=2){
      float4 y0 = yr[k], y1 = yr[k+1];
      a0 = fmaf(y0.x,wr[k].x, fmaf(y0.y,wr[k].y, fmaf(y0.z,wr[k].z, fmaf(y0.w,wr[k].w, a0))));
      a1 = fmaf(y1.x,wr[k+1].x, fmaf(y1.y,wr[k+1].y, fmaf(y1.z,wr[k+1].z, fmaf(y1.w,wr[k+1].w, a1))));
    }
    float a = a0 + a1;
    float s = a;
    #pragma unroll
    for (int off=1;off<64;off<<=1) s += __shfl_xor(s, off, 64);
    float m = s * (1.f/64.f);
    float dv = a - m;
    float s2 = dv*dv;
    #pragma unroll
    for (int off=1;off<64;off<<=1) s2 += __shfl_xor(s2, off, 64);
    float o = dv * rsqrtf(s2*(1.f/64.f) + 1e-5f) * lw + lb;
    h[(size_t)(row0+r)*64 + j] = fmaxf(o, 0.f);
  }
}

// ---------------- mean + last pooling -> enc ----------------
__global__ __launch_bounds__(512) void k_pool(const float* __restrict__ h, float* __restrict__ enc){
  __shared__ float ps[8][64];
  int t = threadIdx.x;
  int w = t >> 6, d = t & 63;
  int b = blockIdx.x;
  const float* hb = h + (size_t)b*LREADx*64;
  float s = 0.f;
  #pragma unroll 8
  for (int i=0;i<64;i++) s += hb[(size_t)(w*64+i)*64 + d];
  ps[w][d] = s;
  __syncthreads();
  if (w == 0){
    float acc = 0.f;
    #pragma unroll
    for (int i=0;i<8;i++) acc += ps[i][d];
    enc[b*128 + d]      = acc * (1.f/512.f);
    enc[b*128 + 64 + d] = hb[(size_t)511*64 + d];
  }
}

// ---------------- q,k projections ----------------
__global__ __launch_bounds__(256) void k_qk(const float* __restrict__ enc,
    const int* __restrict__ sidx, const float* __restrict__ qw, const float* __restrict__ qb,
    const float* __restrict__ kw, const float* __restrict__ kb,
    float* __restrict__ qbuf, float* __restrict__ kbuf){
  int idx = blockIdx.x*256 + threadIdx.x;
  if (idx < NSEQx*64){
    int qi = idx >> 6, j = idx & 63;
    const float* er = enc + (size_t)sidx[qi]*128;
    const float* wr = qw + j*128;
    float a = qb[j];
    for (int k=0;k<32;k++){
      float4 e4 = *(const float4*)(er + k*4);
      float4 w4 = *(const float4*)(wr + k*4);
      a = fmaf(e4.x,w4.x, fmaf(e4.y,w4.y, fmaf(e4.z,w4.z, fmaf(e4.w,w4.w, a))));
    }
    qbuf[idx] = a;
  } else {
    int i2 = idx - NSEQx*64;
    int ki = i2 >> 6, j = i2 & 63;
    const float* er = enc + (size_t)ki*128;
    const float* wr = kw + j*128;
    float a = kb[j];
    for (int k=0;k<32;k++){
      float4 e4 = *(const float4*)(er + k*4);
      float4 w4 = *(const float4*)(wr + k*4);
      a = fmaf(e4.x,w4.x, fmaf(e4.y,w4.y, fmaf(e4.z,w4.z, fmaf(e4.w,w4.w, a))));
    }
    kbuf[i2] = a;
  }
}

// ---------------- scores ----------------
__global__ __launch_bounds__(256) void k_score(const float* __restrict__ qbuf,
    const float* __restrict__ kbuf, const float* __restrict__ mixw,
    const float* __restrict__ mixb, float* __restrict__ out){
  int idx = blockIdx.x*256 + threadIdx.x;
  int ki = idx & 127, qi = idx >> 7;
  const float* qr = qbuf + qi*64;
  const float* kr = kbuf + ki*64;
  float s[4];
  #pragma unroll
  for (int hh=0;hh<4;hh++){
    float a = 0.f;
    #pragma unroll
    for (int k=0;k<4;k++){
      float4 q4 = *(const float4*)(qr + hh*16 + k*4);
      float4 k4 = *(const float4*)(kr + hh*16 + k*4);
      a = fmaf(q4.x,k4.x, fmaf(q4.y,k4.y, fmaf(q4.z,k4.z, fmaf(q4.w,k4.w, a))));
    }
    s[hh] = fmaxf(a, 0.f);
  }
  float best = -1e30f;
  #pragma unroll
  for (int hh=0;hh<4;hh++){
    float v = mixb[hh];
    #pragma unroll
    for (int h2=0;h2<4;h2++) v = fmaf(s[h2], mixw[hh*4+h2], v);
    best = fmaxf(best, v);
  }
  out[idx] = best;
}

// ---------------- transpose x_proj_w once ----------------
__global__ __launch_bounds__(256) void k_trans(const float* __restrict__ xw, float* __restrict__ xwT){
  int i = threadIdx.x + blockIdx.x*256;
  if (i < NLAYER*36*128){
    int l = i / 4608, rem = i % 4608;
    int c = rem >> 7, k = rem & 127;
    xwT[l*4608 + k*36 + c] = xw[i];
  }
}

extern "C" void kernel_launch(void* const* d_in, const int* in_sizes, int n_in,
                              void* d_out, int out_size, void* d_ws, size_t ws_size,
                              hipStream_t stream) {
  (void)in_sizes; (void)n_in; (void)out_size; (void)ws_size;
  const float* reads = (const float*)d_in[0];
  const int*   sidx  = (const int*)d_in[1];
  const float* ew    = (const float*)d_in[2];
  const float* eb    = (const float*)d_in[3];
  const float* inw   = (const float*)d_in[4];
  const float* cw    = (const float*)d_in[5];
  const float* cb    = (const float*)d_in[6];
  const float* xw    = (const float*)d_in[7];
  const float* dtw   = (const float*)d_in[8];
  const float* dtb   = (const float*)d_in[9];
  const float* alog  = (const float*)d_in[10];
  const float* Dp    = (const float*)d_in[11];
  const float* ow    = (const float*)d_in[12];
  const float* lnw   = (const float*)d_in[13];
  const float* lnb   = (const float*)d_in[14];
  const float* qw    = (const float*)d_in[15];
  const float* qb    = (const float*)d_in[16];
  const float* kw    = (const float*)d_in[17];
  const float* kb    = (const float*)d_in[18];
  const float* mixw  = (const float*)d_in[19];
  const float* mixb  = (const float*)d_in[20];

  float* ws  = (float*)d_ws;
  float* h   = ws;                 // 4,194,304
  float* yx  = ws + 4194304;       // 8,388,608 (y)
  float* zs  = ws + 12582912;      // 8,388,608
  float* x   = ws + 20971520;      // 8,388,608
  float* dt  = ws + 29360128;      // 8,388,608
  float* bc  = ws + 37748736;      // 2,097,152
  float* enc = ws + 39845888;      // 16,384
  float* qk  = ws + 39862272;      // 6144 + 8192
  float* xwT = ws + 39876608;      // 13,824

  k_trans<<<54, 256, 0, stream>>>(xw, xwT);
  k_exp<<<16384, 256, 0, stream>>>(reads, ew, eb, h);
  for (int l = 0; l < NLAYER; l++){
    k_xzc <<<2048, 256, 0, stream>>>(h, inw + l*16384, cw + l*512, cb + l*128, x, zs);
    k_xd  <<<512, 256, 0, stream>>>(x, xwT + l*4608, dtw + l*512, dtb + l*128, dt, bc);
    k_scan<<<1024, 256, 0, stream>>>(dt, x, zs, bc, alog + l*2048, Dp + l*128, yx);
    k_out <<<2048, 256, 0, stream>>>(yx, ow + l*8192, lnw + l*64, lnb + l*64, h);
  }
  k_pool <<<128, 512, 0, stream>>>(h, enc);
  k_qk   <<<56, 256, 0, stream>>>(enc, sidx, qw, qb, kw, kb, qk, qk + 6144);
  k_score<<<48, 256, 0, stream>>>(qk, qk + 6144, mixw, mixb, (float*)d_out);
}

// Round 8
// 684.530 us; speedup vs baseline: 1.4111x; 1.1352x over previous
//
#include <hip/hip_runtime.h>
#include <math.h>

#define NLAYER 3
#define LREADx 512
#define NSEQx  96

__device__ __forceinline__ float fsigmoid(float v){ return 1.f/(1.f+__expf(-v)); }
__device__ __forceinline__ float fsoftplus(float v){ return fmaxf(v,0.f) + __logf(1.f + __expf(-fabsf(v))); }

template<int CTRL>
__device__ __forceinline__ float dpp_add(float v){
  int x = __builtin_amdgcn_update_dpp(0, __float_as_int(v), CTRL, 0xF, 0xF, true);
  return v + __int_as_float(x);
}

__device__ __forceinline__ void gload16(const float* g, float* l){
  __builtin_amdgcn_global_load_lds(
      (const __attribute__((address_space(1))) void*)g,
      (__attribute__((address_space(3))) void*)l, 16, 0, 0);
}

// ---------------- expander: h = reads @ ew.T + eb ----------------
__global__ __launch_bounds__(256) void k_exp(const float* __restrict__ reads,
    const float* __restrict__ ew, const float* __restrict__ eb, float* __restrict__ h){
  int idx = blockIdx.x*256 + threadIdx.x;     // NROWS*64
  int d = idx & 63;
  int row = idx >> 6;
  float4 r4 = *(const float4*)(reads + (size_t)row*4);
  float4 w4 = *(const float4*)(ew + d*4);
  h[idx] = fmaf(r4.x,w4.x, fmaf(r4.y,w4.y, fmaf(r4.z,w4.z, fmaf(r4.w,w4.w, eb[d]))));
}

// ---------------- fused in_proj + causal conv(k=4) + silu + z-gate ----------------
// h rows staged in LDS once (coalesced), row loop reads LDS b128 broadcasts
// (no per-row SMEM latency chain). 32 rows/block + 3 warm-up rows.
__global__ __launch_bounds__(256) void k_xzc(const float* __restrict__ h,
    const float* __restrict__ w, const float* __restrict__ cw, const float* __restrict__ cb,
    float* __restrict__ x, float* __restrict__ zsil){
  __shared__ float hstage[35][64];
  __shared__ float xp[35][128];
  int j = threadIdx.x;
  int row0 = blockIdx.x*32;
  int l0 = row0 & 511;
  // stage h rows row0-3 .. row0+31 (zero-pad the 3 pre-rows at batch start)
  for (int i=j; i<560; i+=256){
    int r = i >> 4, q = i & 15;
    float4 v = make_float4(0.f,0.f,0.f,0.f);
    if (!(l0==0 && r<3)) v = *(const float4*)(h + (size_t)(row0-3+r)*64 + q*4);
    *(float4*)&hstage[r][q*4] = v;
  }
  float4 wr[16];
  #pragma unroll
  for (int k=0;k<16;k++) wr[k] = *(const float4*)(w + j*64 + k*4);
  __syncthreads();
  bool isx = j < 128;
  if (isx){
    #pragma unroll
    for (int r=0;r<3;r++){
      const float4* hr = (const float4*)&hstage[r][0];
      float a0=0.f, a1=0.f;
      #pragma unroll
      for (int k=0;k<16;k+=2){
        float4 h0 = hr[k], h1 = hr[k+1];
        a0 = fmaf(h0.x,wr[k].x, fmaf(h0.y,wr[k].y, fmaf(h0.z,wr[k].z, fmaf(h0.w,wr[k].w, a0))));
        a1 = fmaf(h1.x,wr[k+1].x, fmaf(h1.y,wr[k+1].y, fmaf(h1.z,wr[k+1].z, fmaf(h1.w,wr[k+1].w, a1))));
      }
      xp[r][j] = a0 + a1;
    }
  }
  for (int r=0;r<32;r++){
    const float4* hr = (const float4*)&hstage[3+r][0];
    float a0=0.f, a1=0.f;
    #pragma unroll
    for (int k=0;k<16;k+=2){
      float4 h0 = hr[k], h1 = hr[k+1];
      a0 = fmaf(h0.x,wr[k].x, fmaf(h0.y,wr[k].y, fmaf(h0.z,wr[k].z, fmaf(h0.w,wr[k].w, a0))));
      a1 = fmaf(h1.x,wr[k+1].x, fmaf(h1.y,wr[k+1].y, fmaf(h1.z,wr[k+1].z, fmaf(h1.w,wr[k+1].w, a1))));
    }
    float a = a0 + a1;
    if (isx) xp[3+r][j] = a;
    else     zsil[(size_t)(row0+r)*128 + (j-128)] = a * fsigmoid(a);
  }
  __syncthreads();
  int c = j & 127, half = j >> 7;
  float4 w4 = *(const float4*)(cw + c*4);
  float bv = cb[c];
  #pragma unroll
  for (int r=half*16; r<half*16+16; r++){
    float a = fmaf(xp[r][c],w4.x, fmaf(xp[r+1][c],w4.y, fmaf(xp[r+2][c],w4.z,
              fmaf(xp[r+3][c],w4.w, bv))));
    x[(size_t)(row0+r)*128 + c] = a * fsigmoid(a);
  }
}

// ---------------- x_proj (K=128 split 2x64, N=36) + dt softplus + B/C interleave ----------------
__global__ __launch_bounds__(256) void k_xd(const float* __restrict__ x,
    const float* __restrict__ xwT, const float* __restrict__ dtw,
    const float* __restrict__ dtb, float* __restrict__ dt, float* __restrict__ bc){
  __shared__ float  accs[128][37];
  __shared__ float4 xd03[128];
  __shared__ float  bcs[128][33];
  int t = threadIdx.x;
  int r = t & 127, kh = t >> 7;
  int row = blockIdx.x*128 + r;
  float acc[36];
  #pragma unroll
  for (int c=0;c<36;c++) acc[c]=0.f;
  const float4* xr = (const float4*)(x + (size_t)row*128 + kh*64);
  for (int k4=0;k4<16;k4++){
    float4 xv = xr[k4];
    float xa[4] = {xv.x, xv.y, xv.z, xv.w};
    #pragma unroll
    for (int kk=0;kk<4;kk++){
      const float* wk = xwT + (kh*64 + k4*4+kk)*36;
      #pragma unroll
      for (int c=0;c<36;c++) acc[c] = fmaf(xa[kk], wk[c], acc[c]);
    }
  }
  if (kh == 1){
    #pragma unroll
    for (int c=0;c<36;c++) accs[r][c] = acc[c];
  }
  __syncthreads();
  if (kh == 0){
    #pragma unroll
    for (int c=0;c<36;c++) acc[c] += accs[r][c];
    xd03[r] = make_float4(acc[0],acc[1],acc[2],acc[3]);
    #pragma unroll
    for (int nn=0;nn<16;nn++){ bcs[r][2*nn] = acc[4+nn]; bcs[r][2*nn+1] = acc[20+nn]; }
  }
  __syncthreads();
  int d = t & 127, half = t >> 7;
  float4 w4 = *(const float4*)(dtw + d*4);
  float bv = dtb[d];
  size_t row0 = (size_t)blockIdx.x*128;
  for (int rr=half; rr<128; rr+=2){
    float4 s4 = xd03[rr];
    float v = fmaf(s4.x,w4.x, fmaf(s4.y,w4.y, fmaf(s4.z,w4.z, fmaf(s4.w,w4.w, bv))));
    dt[(row0+rr)*128 + d] = fsoftplus(v);
  }
  for (int i=t; i<128*32; i+=256){
    int rr = i >> 5, cc = i & 31;
    bc[(row0+rr)*32 + cc] = bcs[rr][cc];
  }
}

// ---------------- selective scan: 8 lanes/d, 2 n-states in VGPRs ----------------
// block = (b, d-group of 32), 256 thr = 32 d x 8 np; thread owns n=np and np+8.
// dt/x/bc double-buffered via global_load_lds; z single-buffered; counted vmcnt.
// 8-group reduce via row_shl (out[i]=in[i+n]; group-base lanes np==0 are clean).
__global__ __launch_bounds__(256) void k_scan(const float* __restrict__ dt,
    const float* __restrict__ x, const float* __restrict__ zsil,
    const float* __restrict__ bc, const float* __restrict__ alog,
    const float* __restrict__ Dp, float* __restrict__ y){
  __shared__ float dtb_[2][2048];
  __shared__ float xb [2][2048];
  __shared__ float bcb[2][2048];
  __shared__ float zb [2048];
  __shared__ float ys [2048];
  int t = threadIdx.x;
  int b  = blockIdx.x & 127;          // blocks of same b land on same XCD (128%8==0)
  int dg = blockIdx.x >> 7;           // 0..3
  int wv = __builtin_amdgcn_readfirstlane(t >> 6);
  int ln = t & 63;
  int dl = t >> 3;                    // 0..31
  int np = t & 7;
  int d  = dg*32 + dl;
  float aL1 = -__expf(alog[d*16 + np])     * 1.44269504f;
  float aL2 = -__expf(alog[d*16 + np + 8]) * 1.44269504f;
  float Dv  = Dp[d];
  float hs1 = 0.f, hs2 = 0.f;
  size_t base  = (size_t)b*512*128 + (size_t)dg*32;
  size_t baseb = (size_t)b*512*32;
  int lrow = wv*16 + (ln>>3), lcol = (ln&7)*4;
  const float* dtA = dt   + base  + (size_t)lrow*128 + lcol;
  const float* xA  = x    + base  + (size_t)lrow*128 + lcol;
  const float* zA  = zsil + base  + (size_t)lrow*128 + lcol;
  const float* bA  = bc   + baseb + (size_t)lrow*32  + lcol;
  // prologue: chunk 0 dt/x/bc (6 DMAs per wave)
  gload16(dtA,      &dtb_[0][wv*512]);
  gload16(dtA+1024, &dtb_[0][wv*512+256]);
  gload16(xA,       &xb [0][wv*512]);
  gload16(xA+1024,  &xb [0][wv*512+256]);
  gload16(bA,       &bcb[0][wv*512]);
  gload16(bA+256,   &bcb[0][wv*512+256]);
  for (int c=0;c<8;c++){
    int buf = c & 1;
    gload16(zA + c*8192,        &zb[wv*512]);
    gload16(zA + c*8192 + 1024, &zb[wv*512+256]);
    if (c < 7){
      gload16(dtA + (c+1)*8192,        &dtb_[buf^1][wv*512]);
      gload16(dtA + (c+1)*8192 + 1024, &dtb_[buf^1][wv*512+256]);
      gload16(xA  + (c+1)*8192,        &xb [buf^1][wv*512]);
      gload16(xA  + (c+1)*8192 + 1024, &xb [buf^1][wv*512+256]);
      gload16(bA  + (c+1)*2048,        &bcb[buf^1][wv*512]);
      gload16(bA  + (c+1)*2048 + 256,  &bcb[buf^1][wv*512+256]);
    }
    if (c < 7) asm volatile("s_waitcnt vmcnt(8)" ::: "memory");
    else       asm volatile("s_waitcnt vmcnt(2)" ::: "memory");
    __builtin_amdgcn_s_barrier();
    #pragma unroll 8
    for (int l=0;l<64;l++){
      float dtv = dtb_[buf][l*32 + dl];
      float xv  = xb [buf][l*32 + dl];
      float2 b1 = *(const float2*)&bcb[buf][l*32 + 2*np];
      float2 b2 = *(const float2*)&bcb[buf][l*32 + 2*np + 16];
      float e1 = __builtin_amdgcn_exp2f(dtv * aL1);
      float e2 = __builtin_amdgcn_exp2f(dtv * aL2);
      float dtx = dtv * xv;
      hs1 = fmaf(e1, hs1, dtx * b1.x);
      hs2 = fmaf(e2, hs2, dtx * b2.x);
      float p = fmaf(hs2, b2.y, hs1 * b1.y);
      p = dpp_add<0x101>(p);   // row_shl:1  (out[i]=in[i+1])
      p = dpp_add<0x102>(p);   // row_shl:2
      p = dpp_add<0x104>(p);   // row_shl:4
      if (np == 0) ys[l*32 + dl] = fmaf(xv, Dv, p);
    }
    if (c < 7) asm volatile("s_waitcnt lgkmcnt(0) vmcnt(6)" ::: "memory");
    else       asm volatile("s_waitcnt lgkmcnt(0) vmcnt(0)" ::: "memory");
    __builtin_amdgcn_s_barrier();
    size_t yb = base + (size_t)c*8192;
    #pragma unroll
    for (int i=0;i<8;i++){
      int idx = i*256 + t;
      int l = idx >> 5, de = idx & 31;
      y[yb + (size_t)l*128 + de] = ys[idx] * zb[idx];
    }
    asm volatile("s_waitcnt lgkmcnt(0)" ::: "memory");
    __builtin_amdgcn_s_barrier();
  }
}

// ---------------- out proj + LayerNorm + ReLU ----------------
__global__ __launch_bounds__(256) void k_out(const float* __restrict__ y,
    const float* __restrict__ ow, const float* __restrict__ lnw,
    const float* __restrict__ lnb, float* __restrict__ h){
  int t = threadIdx.x;
  int j = t & 63;
  int rg = __builtin_amdgcn_readfirstlane(t >> 6);
  int row0 = blockIdx.x*32 + rg*8;
  float4 wr[32];
  #pragma unroll
  for (int k=0;k<32;k++) wr[k] = *(const float4*)(ow + j*128 + k*4);
  float lw = lnw[j], lb = lnb[j];
  for (int r=0;r<8;r++){
    const float4* yr = (const float4*)(y + (size_t)(row0+r)*128);  // uniform -> s_load
    float a0=0.f, a1=0.f;
    #pragma unroll
    for (int k=0;k<32;k+=2){
      float4 y0 = yr[k], y1 = yr[k+1];
      a0 = fmaf(y0.x,wr[k].x, fmaf(y0.y,wr[k].y, fmaf(y0.z,wr[k].z, fmaf(y0.w,wr[k].w, a0))));
      a1 = fmaf(y1.x,wr[k+1].x, fmaf(y1.y,wr[k+1].y, fmaf(y1.z,wr[k+1].z, fmaf(y1.w,wr[k+1].w, a1))));
    }
    float a = a0 + a1;
    float s = a;
    #pragma unroll
    for (int off=1;off<64;off<<=1) s += __shfl_xor(s, off, 64);
    float m = s * (1.f/64.f);
    float dv = a - m;
    float s2 = dv*dv;
    #pragma unroll
    for (int off=1;off<64;off<<=1) s2 += __shfl_xor(s2, off, 64);
    float o = dv * rsqrtf(s2*(1.f/64.f) + 1e-5f) * lw + lb;
    h[(size_t)(row0+r)*64 + j] = fmaxf(o, 0.f);
  }
}

// ---------------- mean + last pooling -> enc ----------------
__global__ __launch_bounds__(512) void k_pool(const float* __restrict__ h, float* __restrict__ enc){
  __shared__ float ps[8][64];
  int t = threadIdx.x;
  int w = t >> 6, d = t & 63;
  int b = blockIdx.x;
  const float* hb = h + (size_t)b*LREADx*64;
  float s = 0.f;
  #pragma unroll 8
  for (int i=0;i<64;i++) s += hb[(size_t)(w*64+i)*64 + d];
  ps[w][d] = s;
  __syncthreads();
  if (w == 0){
    float acc = 0.f;
    #pragma unroll
    for (int i=0;i<8;i++) acc += ps[i][d];
    enc[b*128 + d]      = acc * (1.f/512.f);
    enc[b*128 + 64 + d] = hb[(size_t)511*64 + d];
  }
}

// ---------------- q,k projections ----------------
__global__ __launch_bounds__(256) void k_qk(const float* __restrict__ enc,
    const int* __restrict__ sidx, const float* __restrict__ qw, const float* __restrict__ qb,
    const float* __restrict__ kw, const float* __restrict__ kb,
    float* __restrict__ qbuf, float* __restrict__ kbuf){
  int idx = blockIdx.x*256 + threadIdx.x;
  if (idx < NSEQx*64){
    int qi = idx >> 6, j = idx & 63;
    const float* er = enc + (size_t)sidx[qi]*128;
    const float* wr = qw + j*128;
    float a = qb[j];
    for (int k=0;k<32;k++){
      float4 e4 = *(const float4*)(er + k*4);
      float4 w4 = *(const float4*)(wr + k*4);
      a = fmaf(e4.x,w4.x, fmaf(e4.y,w4.y, fmaf(e4.z,w4.z, fmaf(e4.w,w4.w, a))));
    }
    qbuf[idx] = a;
  } else {
    int i2 = idx - NSEQx*64;
    int ki = i2 >> 6, j = i2 & 63;
    const float* er = enc + (size_t)ki*128;
    const float* wr = kw + j*128;
    float a = kb[j];
    for (int k=0;k<32;k++){
      float4 e4 = *(const float4*)(er + k*4);
      float4 w4 = *(const float4*)(wr + k*4);
      a = fmaf(e4.x,w4.x, fmaf(e4.y,w4.y, fmaf(e4.z,w4.z, fmaf(e4.w,w4.w, a))));
    }
    kbuf[i2] = a;
  }
}

// ---------------- scores ----------------
__global__ __launch_bounds__(256) void k_score(const float* __restrict__ qbuf,
    const float* __restrict__ kbuf, const float* __restrict__ mixw,
    const float* __restrict__ mixb, float* __restrict__ out){
  int idx = blockIdx.x*256 + threadIdx.x;
  int ki = idx & 127, qi = idx >> 7;
  const float* qr = qbuf + qi*64;
  const float* kr = kbuf + ki*64;
  float s[4];
  #pragma unroll
  for (int hh=0;hh<4;hh++){
    float a = 0.f;
    #pragma unroll
    for (int k=0;k<4;k++){
      float4 q4 = *(const float4*)(qr + hh*16 + k*4);
      float4 k4 = *(const float4*)(kr + hh*16 + k*4);
      a = fmaf(q4.x,k4.x, fmaf(q4.y,k4.y, fmaf(q4.z,k4.z, fmaf(q4.w,k4.w, a))));
    }
    s[hh] = fmaxf(a, 0.f);
  }
  float best = -1e30f;
  #pragma unroll
  for (int hh=0;hh<4;hh++){
    float v = mixb[hh];
    #pragma unroll
    for (int h2=0;h2<4;h2++) v = fmaf(s[h2], mixw[hh*4+h2], v);
    best = fmaxf(best, v);
  }
  out[idx] = best;
}

// ---------------- transpose x_proj_w once ----------------
__global__ __launch_bounds__(256) void k_trans(const float* __restrict__ xw, float* __restrict__ xwT){
  int i = threadIdx.x + blockIdx.x*256;
  if (i < NLAYER*36*128){
    int l = i / 4608, rem = i % 4608;
    int c = rem >> 7, k = rem & 127;
    xwT[l*4608 + k*36 + c] = xw[i];
  }
}

extern "C" void kernel_launch(void* const* d_in, const int* in_sizes, int n_in,
                              void* d_out, int out_size, void* d_ws, size_t ws_size,
                              hipStream_t stream) {
  (void)in_sizes; (void)n_in; (void)out_size; (void)ws_size;
  const float* reads = (const float*)d_in[0];
  const int*   sidx  = (const int*)d_in[1];
  const float* ew    = (const float*)d_in[2];
  const float* eb    = (const float*)d_in[3];
  const float* inw   = (const float*)d_in[4];
  const float* cw    = (const float*)d_in[5];
  const float* cb    = (const float*)d_in[6];
  const float* xw    = (const float*)d_in[7];
  const float* dtw   = (const float*)d_in[8];
  const float* dtb   = (const float*)d_in[9];
  const float* alog  = (const float*)d_in[10];
  const float* Dp    = (const float*)d_in[11];
  const float* ow    = (const float*)d_in[12];
  const float* lnw   = (const float*)d_in[13];
  const float* lnb   = (const float*)d_in[14];
  const float* qw    = (const float*)d_in[15];
  const float* qb    = (const float*)d_in[16];
  const float* kw    = (const float*)d_in[17];
  const float* kb    = (const float*)d_in[18];
  const float* mixw  = (const float*)d_in[19];
  const float* mixb  = (const float*)d_in[20];

  float* ws  = (float*)d_ws;
  float* h   = ws;                 // 4,194,304
  float* yx  = ws + 4194304;       // 8,388,608 (y)
  float* zs  = ws + 12582912;      // 8,388,608
  float* x   = ws + 20971520;      // 8,388,608
  float* dt  = ws + 29360128;      // 8,388,608
  float* bc  = ws + 37748736;      // 2,097,152
  float* enc = ws + 39845888;      // 16,384
  float* qk  = ws + 39862272;      // 6144 + 8192
  float* xwT = ws + 39876608;      // 13,824

  k_trans<<<54, 256, 0, stream>>>(xw, xwT);
  k_exp<<<16384, 256, 0, stream>>>(reads, ew, eb, h);
  for (int l = 0; l < NLAYER; l++){
    k_xzc <<<2048, 256, 0, stream>>>(h, inw + l*16384, cw + l*512, cb + l*128, x, zs);
    k_xd  <<<512, 256, 0, stream>>>(x, xwT + l*4608, dtw + l*512, dtb + l*128, dt, bc);
    k_scan<<<512, 256, 0, stream>>>(dt, x, zs, bc, alog + l*2048, Dp + l*128, yx);
    k_out <<<2048, 256, 0, stream>>>(yx, ow + l*8192, lnw + l*64, lnb + l*64, h);
  }
  k_pool <<<128, 512, 0, stream>>>(h, enc);
  k_qk   <<<56, 256, 0, stream>>>(enc, sidx, qw, qb, kw, kb, qk, qk + 6144);
  k_score<<<48, 256, 0, stream>>>(qk, qk + 6144, mixw, mixb, (float*)d_out);
}